// Round 11
// baseline (538.313 us; speedup 1.0000x reference)
//
#include <hip/hip_runtime.h>
#include <hip/hip_bf16.h>
#include <math.h>

#define BB 64
#define T 128
#define DD 768
#define H 256
#define JJ 128
#define NSPAN 8256
#define KTOP 256
#define SCAP 1024
#define MARGIN 0.03f

typedef __attribute__((ext_vector_type(8))) short bf16x8;
typedef __attribute__((ext_vector_type(4))) float f32x4;

__device__ inline unsigned short bfrne(float x) {
    unsigned u = __float_as_uint(x);
    return (unsigned short)((u + 0x7FFFu + ((u >> 16) & 1u)) >> 16);
}

__device__ inline unsigned pk2(float x, float y) {
    float2 f; f.x = x; f.y = y;
    __hip_bfloat162 h = __float22bfloat162_rn(f);
    return *reinterpret_cast<unsigned*>(&h);
}

// ---------------------------------------------------------------------------
// Kernel 0 (merged prep)
// ---------------------------------------------------------------------------
__global__ __launch_bounds__(256) void prep_kernel(
    int* __restrict__ s_idx, int* __restrict__ e_idx,
    const float* __restrict__ W1, unsigned short* __restrict__ Wpk,
    const float* __restrict__ tie, const float* __restrict__ Winj,
    const float* __restrict__ binj, float* __restrict__ injv)
{
    const int blk = blockIdx.x;
    const int t = threadIdx.x;
    if (blk == 0) {
        if (t < T) {
            int s = t;
            int start = s * T - (s * (s - 1)) / 2;
            int len = T - s;
            for (int i = 0; i < len; ++i) {
                s_idx[start + i] = s;
                e_idx[start + i] = s + i;
            }
        }
    } else if (blk <= 256) {
        int idx = (blk - 1) * 256 + t;   // 65536 total
        int j  = idx & 7;
        int l  = (idx >> 3) & 63;
        int kc = (idx >> 9) & 7;
        int ct = idx >> 12;
        int k = kc * 32 + (l >> 4) * 8 + j;
        int n = ct * 16 + (l & 15);
        Wpk[idx] = bfrne(W1[k * 256 + n]);
    } else {
        int b = blk - 257;
        __shared__ float tb[JJ];
        if (t < JJ) tb[t] = tie[b * JJ + t];
        __syncthreads();
        float a = binj[t];
        for (int j = 0; j < JJ; ++j)
            a = fmaf(tb[j], Winj[j * H + t], a);
        injv[b * H + t] = a;
    }
}

// ---------------------------------------------------------------------------
// Kernel 1: proj GEMM v3 (unchanged)
// ---------------------------------------------------------------------------
__global__ __launch_bounds__(256) void proj_kernel(
    const float* __restrict__ X,
    const float* __restrict__ Wa, const float* __restrict__ ba,
    const float* __restrict__ Wb, const float* __restrict__ bb,
    float* __restrict__ AE)
{
    const int m0 = blockIdx.x * 64;
    const int cb = blockIdx.y;
    const float* W    = (cb < 2) ? Wa : Wb;
    const float* bias = (cb < 2) ? ba : bb;
    const int wc0 = (cb & 1) * 128;
    const int oc0 = (cb < 2) ? wc0 : (256 + wc0);

    __shared__ float Xs[64 * 36];
    __shared__ float Wl[32 * 132];

    const int t  = threadIdx.x;
    const int tx = t & 15;
    const int ty = t >> 4;

    const int xrow = t >> 2;
    const int xk8  = (t & 3) * 8;
    const int wrow = t >> 4;
    const int wcol = (t & 15) * 8;

    float4 xr[2], w0r[2], w1r[2];
    {
        const float* xp = &X[(size_t)(m0 + xrow) * DD + xk8];
        xr[0] = *(const float4*)&xp[0]; xr[1] = *(const float4*)&xp[4];
        const float* wp0 = &W[(size_t)wrow * 256 + wc0 + wcol];
        w0r[0] = *(const float4*)&wp0[0]; w0r[1] = *(const float4*)&wp0[4];
        const float* wp1 = &W[(size_t)(wrow + 16) * 256 + wc0 + wcol];
        w1r[0] = *(const float4*)&wp1[0]; w1r[1] = *(const float4*)&wp1[4];
    }

    float acc[4][8];
#pragma unroll
    for (int i = 0; i < 4; ++i)
#pragma unroll
        for (int j = 0; j < 8; ++j) acc[i][j] = 0.f;

    for (int it = 0; it < 24; ++it) {
        __syncthreads();
        *(float4*)&Xs[xrow * 36 + xk8]           = xr[0];
        *(float4*)&Xs[xrow * 36 + xk8 + 4]       = xr[1];
        *(float4*)&Wl[wrow * 132 + wcol]         = w0r[0];
        *(float4*)&Wl[wrow * 132 + wcol + 4]     = w0r[1];
        *(float4*)&Wl[(wrow+16) * 132 + wcol]    = w1r[0];
        *(float4*)&Wl[(wrow+16) * 132 + wcol + 4]= w1r[1];
        __syncthreads();
        if (it + 1 < 24) {
            const int kk = (it + 1) * 32;
            const float* xp = &X[(size_t)(m0 + xrow) * DD + kk + xk8];
            xr[0] = *(const float4*)&xp[0]; xr[1] = *(const float4*)&xp[4];
            const float* wp0 = &W[(size_t)(kk + wrow) * 256 + wc0 + wcol];
            w0r[0] = *(const float4*)&wp0[0]; w0r[1] = *(const float4*)&wp0[4];
            const float* wp1 = &W[(size_t)(kk + wrow + 16) * 256 + wc0 + wcol];
            w1r[0] = *(const float4*)&wp1[0]; w1r[1] = *(const float4*)&wp1[4];
        }
#pragma unroll
        for (int k = 0; k < 32; ++k) {
            float4 wv0 = *(const float4*)&Wl[k * 132 + tx * 8];
            float4 wv1 = *(const float4*)&Wl[k * 132 + tx * 8 + 4];
            float wq[8] = {wv0.x, wv0.y, wv0.z, wv0.w, wv1.x, wv1.y, wv1.z, wv1.w};
            float xq[4];
#pragma unroll
            for (int i = 0; i < 4; ++i)
                xq[i] = Xs[(ty * 4 + i) * 36 + k];
#pragma unroll
            for (int i = 0; i < 4; ++i)
#pragma unroll
                for (int j = 0; j < 8; ++j)
                    acc[i][j] = fmaf(xq[i], wq[j], acc[i][j]);
        }
    }

    float bq[8];
#pragma unroll
    for (int j = 0; j < 8; ++j) bq[j] = bias[wc0 + tx * 8 + j];
#pragma unroll
    for (int i = 0; i < 4; ++i) {
        const size_t row = m0 + ty * 4 + i;
        float4 o0, o1;
        o0.x = acc[i][0] + bq[0]; o0.y = acc[i][1] + bq[1];
        o0.z = acc[i][2] + bq[2]; o0.w = acc[i][3] + bq[3];
        o1.x = acc[i][4] + bq[4]; o1.y = acc[i][5] + bq[5];
        o1.z = acc[i][6] + bq[6]; o1.w = acc[i][7] + bq[7];
        *(float4*)&AE[row * 512 + oc0 + tx * 8]     = o0;
        *(float4*)&AE[row * 512 + oc0 + tx * 8 + 4] = o1;
    }
}

// ---------------------------------------------------------------------------
// Kernel 2: approx scorer — pair-pipelined persistent blocks.
// Grid 256 (1 block/CU), 512 threads. Per iteration: TWO 16-span tiles
// (one barrier, 4 MFMA chains/wave, loads in flight across the whole
// compute span). XCD-local batch mapping kept. Scores bit-identical to R10.
// ---------------------------------------------------------------------------
__global__ __launch_bounds__(512, 2) void approx_kernel(
    const float* __restrict__ AE,
    const unsigned short* __restrict__ Wpk,
    const float* __restrict__ bs1, const float* __restrict__ Ws2,
    const float* __restrict__ bs2g,
    const int* __restrict__ s_idx, const int* __restrict__ e_idx,
    const int* __restrict__ maskp,
    float* __restrict__ scores)
{
    const int bid   = blockIdx.x;       // 0..255
    const int r     = bid & 7;
    const int q     = bid >> 3;         // 0..31
    const int g     = q >> 2;           // batch group 0..7
    const int chunk = q & 3;
    const int b     = g * 8 + r;
    const int p0    = chunk * 65;                       // pair base (258 pairs)
    const int cnt   = (258 - p0 < 65) ? (258 - p0) : 65;

    __shared__ __align__(16) unsigned short rshf[2][2][8][64][8];  // 32 KB
    __shared__ float pslice[2][8][32];                             // 2 KB

    const int t      = threadIdx.x;
    const int w      = t >> 6;
    const int lane   = t & 63;
    const int lrow16 = lane & 15;
    const int quad   = lane >> 4;

    // held B fragments: ct = 2w + c
    bf16x8 bfr[2][8];
    float b1c[2], w2c[2];
#pragma unroll
    for (int c = 0; c < 2; ++c) {
#pragma unroll
        for (int kc = 0; kc < 8; ++kc)
            bfr[c][kc] = *(const bf16x8*)&Wpk[((((2 * w + c) * 8 + kc) * 64) + lane) * 8];
        int col = (2 * w + c) * 16 + lrow16;
        b1c[c] = bs1[col];
        w2c[c] = Ws2[col];
    }
    const float bs2v = bs2g[0];

    const float* Abase = AE + (size_t)b * T * 512;
    // staging geometry: thread -> span sp32 (0..31), 16-float k-seg kseg (0..15)
    const int sp32 = t >> 4;
    const int tau  = sp32 >> 4;         // tile in pair
    const int lrow = sp32 & 15;
    const int kseg = t & 15;
    const int kc_s = kseg >> 1;
    const int q0   = (kseg & 1) * 2;
    const int sl0  = (q0 * 16 + lrow + kc_s) & 63;
    const int sl1  = ((q0 + 1) * 16 + lrow + kc_s) & 63;

    // prologue: stage pair 0 into buffer 0
    {
        int n = (2 * p0 + tau) * 16 + lrow;
        int s = s_idx[n], e = e_idx[n];
        const float* Ar = Abase + (size_t)s * 512 + kseg * 16;
        const float* Er = Abase + (size_t)e * 512 + 256 + kseg * 16;
        float4 a0 = *(const float4*)&Ar[0],  a1 = *(const float4*)&Ar[4];
        float4 a2 = *(const float4*)&Ar[8],  a3 = *(const float4*)&Ar[12];
        float4 e0 = *(const float4*)&Er[0],  e1 = *(const float4*)&Er[4];
        float4 e2 = *(const float4*)&Er[8],  e3 = *(const float4*)&Er[12];
        uint4 v0, v1;
        v0.x = pk2(fmaxf(a0.x + e0.x, 0.f), fmaxf(a0.y + e0.y, 0.f));
        v0.y = pk2(fmaxf(a0.z + e0.z, 0.f), fmaxf(a0.w + e0.w, 0.f));
        v0.z = pk2(fmaxf(a1.x + e1.x, 0.f), fmaxf(a1.y + e1.y, 0.f));
        v0.w = pk2(fmaxf(a1.z + e1.z, 0.f), fmaxf(a1.w + e1.w, 0.f));
        v1.x = pk2(fmaxf(a2.x + e2.x, 0.f), fmaxf(a2.y + e2.y, 0.f));
        v1.y = pk2(fmaxf(a2.z + e2.z, 0.f), fmaxf(a2.w + e2.w, 0.f));
        v1.z = pk2(fmaxf(a3.x + e3.x, 0.f), fmaxf(a3.y + e3.y, 0.f));
        v1.w = pk2(fmaxf(a3.z + e3.z, 0.f), fmaxf(a3.w + e3.w, 0.f));
        *(uint4*)&rshf[0][tau][kc_s][sl0][0] = v0;
        *(uint4*)&rshf[0][tau][kc_s][sl1][0] = v1;
    }
    __syncthreads();

    for (int tt = 0; tt < cnt; ++tt) {
        const int cur = tt & 1;
        // issue prefetch loads for pair tt+1 (consumed after compute)
        float4 a0, a1, a2, a3, e0, e1, e2, e3;
        const bool pf = (tt + 1 < cnt);
        if (pf) {
            int n = (2 * (p0 + tt + 1) + tau) * 16 + lrow;
            int s = s_idx[n], e = e_idx[n];
            const float* Ar = Abase + (size_t)s * 512 + kseg * 16;
            const float* Er = Abase + (size_t)e * 512 + 256 + kseg * 16;
            a0 = *(const float4*)&Ar[0];  a1 = *(const float4*)&Ar[4];
            a2 = *(const float4*)&Ar[8];  a3 = *(const float4*)&Ar[12];
            e0 = *(const float4*)&Er[0];  e1 = *(const float4*)&Er[4];
            e2 = *(const float4*)&Er[8];  e3 = *(const float4*)&Er[12];
        }
        // compute both tiles of pair tt: 4 independent chains
        f32x4 acc[2][2];
#pragma unroll
        for (int a = 0; a < 2; ++a)
#pragma unroll
            for (int c = 0; c < 2; ++c) acc[a][c] = (f32x4){0.f, 0.f, 0.f, 0.f};
#pragma unroll
        for (int kc = 0; kc < 8; ++kc) {
            const int rot = (lane + kc) & 63;
            bf16x8 x0 = *(const bf16x8*)&rshf[cur][0][kc][rot][0];
            bf16x8 x1 = *(const bf16x8*)&rshf[cur][1][kc][rot][0];
            acc[0][0] = __builtin_amdgcn_mfma_f32_16x16x32_bf16(x0, bfr[0][kc], acc[0][0], 0, 0, 0);
            acc[1][0] = __builtin_amdgcn_mfma_f32_16x16x32_bf16(x1, bfr[0][kc], acc[1][0], 0, 0, 0);
            acc[0][1] = __builtin_amdgcn_mfma_f32_16x16x32_bf16(x0, bfr[1][kc], acc[0][1], 0, 0, 0);
            acc[1][1] = __builtin_amdgcn_mfma_f32_16x16x32_bf16(x1, bfr[1][kc], acc[1][1], 0, 0, 0);
        }
        // fold layer-2 per tile, reduce over 16 lanes, write pslice
#pragma unroll
        for (int a = 0; a < 2; ++a) {
            float ps[4];
#pragma unroll
            for (int rr = 0; rr < 4; ++rr)
                ps[rr] = fmaxf(acc[a][0][rr] + b1c[0], 0.f) * w2c[0]
                       + fmaxf(acc[a][1][rr] + b1c[1], 0.f) * w2c[1];
#pragma unroll
            for (int off = 1; off < 16; off <<= 1)
#pragma unroll
                for (int rr = 0; rr < 4; ++rr)
                    ps[rr] += __shfl_xor(ps[rr], off, 16);
            if (lrow16 == 0) {
                float4 v; v.x = ps[0]; v.y = ps[1]; v.z = ps[2]; v.w = ps[3];
                *(float4*)&pslice[cur][w][a * 16 + quad * 4] = v;
            }
        }
        // convert + stage pair tt+1 (vmcnt wait lands here, ~full-iter distance)
        if (pf) {
            uint4 v0, v1;
            v0.x = pk2(fmaxf(a0.x + e0.x, 0.f), fmaxf(a0.y + e0.y, 0.f));
            v0.y = pk2(fmaxf(a0.z + e0.z, 0.f), fmaxf(a0.w + e0.w, 0.f));
            v0.z = pk2(fmaxf(a1.x + e1.x, 0.f), fmaxf(a1.y + e1.y, 0.f));
            v0.w = pk2(fmaxf(a1.z + e1.z, 0.f), fmaxf(a1.w + e1.w, 0.f));
            v1.x = pk2(fmaxf(a2.x + e2.x, 0.f), fmaxf(a2.y + e2.y, 0.f));
            v1.y = pk2(fmaxf(a2.z + e2.z, 0.f), fmaxf(a2.w + e2.w, 0.f));
            v1.z = pk2(fmaxf(a3.x + e3.x, 0.f), fmaxf(a3.y + e3.y, 0.f));
            v1.w = pk2(fmaxf(a3.z + e3.z, 0.f), fmaxf(a3.w + e3.w, 0.f));
            *(uint4*)&rshf[cur ^ 1][tau][kc_s][sl0][0] = v0;
            *(uint4*)&rshf[cur ^ 1][tau][kc_s][sl1][0] = v1;
        }
        __syncthreads();
        // fold across waves + store pair tt's 32 scores
        if (t < 32) {
            int tl = t >> 4, idx = t & 15;
            int n = (2 * (p0 + tt) + tl) * 16 + idx;
            float sc = bs2v;
#pragma unroll
            for (int ww = 0; ww < 8; ++ww) sc += pslice[cur][ww][tl * 16 + idx];
            int s = s_idx[n], e = e_idx[n];
            bool m = (maskp[b * T + s] != 0) && (maskp[b * T + e] != 0);
            scores[(size_t)b * NSPAN + n] = m ? sc : -INFINITY;
        }
    }
}

// ---------------------------------------------------------------------------
// Kernel 3: shortlist select — byte-wise radix (unchanged)
// ---------------------------------------------------------------------------
__global__ __launch_bounds__(256) void select_kernel(
    const float* __restrict__ scores,
    int* __restrict__ shortlist, int* __restrict__ slcnt)
{
    const int b = blockIdx.x;
    const int t = threadIdx.x;
    __shared__ unsigned su[NSPAN];
    __shared__ int hist[256];
    __shared__ unsigned s_prefix;
    __shared__ int s_remaining;
    __shared__ int wave_keep[4];

    const float* sc = scores + (size_t)b * NSPAN;
    for (int i = t; i < NSPAN; i += 256) {
        unsigned ub = __float_as_uint(sc[i]);
        su[i] = (ub & 0x80000000u) ? ~ub : (ub | 0x80000000u);
    }
    __syncthreads();

    unsigned prefix = 0;
    int remaining = KTOP;
    for (int d = 3; d >= 0; --d) {
        hist[t] = 0;
        __syncthreads();
        const int sh = d * 8;
        for (int i = t; i < NSPAN; i += 256) {
            unsigned u = su[i];
            bool match = (d == 3) || ((u >> (sh + 8)) == (prefix >> (sh + 8)));
            if (match) atomicAdd(&hist[(u >> sh) & 255], 1);
        }
        __syncthreads();
        if (t == 0) {
            int acc = 0, v = 255;
            for (; v > 0; --v) {
                int h = hist[v];
                if (acc + h >= remaining) break;
                acc += h;
            }
            s_prefix = prefix | ((unsigned)v << sh);
            s_remaining = remaining - acc;
        }
        __syncthreads();
        prefix = s_prefix;
        remaining = s_remaining;
        __syncthreads();
    }

    unsigned ub = (prefix & 0x80000000u) ? (prefix & 0x7FFFFFFFu) : ~prefix;
    float kthf = __uint_as_float(ub);
    float tau = kthf - MARGIN;
    unsigned tb = __float_as_uint(tau);
    unsigned ktau = (tb & 0x80000000u) ? ~tb : (tb | 0x80000000u);

    const int wid = t >> 6, lane = t & 63;
    int base = 0;
    const unsigned long long ltmask = (1ull << lane) - 1ull;
    for (int c0 = 0; c0 < NSPAN; c0 += 256) {
        int n = c0 + t;
        bool keep = (n < NSPAN) && (su[n] >= ktau);
        unsigned long long bk = __ballot(keep);
        int before = __popcll(bk & ltmask);
        if (lane == 0) wave_keep[wid] = __popcll(bk);
        __syncthreads();
        int kb = base;
        for (int wv = 0; wv < wid; ++wv) kb += wave_keep[wv];
        if (keep) {
            int pos = kb + before;
            if (pos < SCAP) shortlist[b * SCAP + pos] = n;
        }
        for (int wv = 0; wv < 4; ++wv) base += wave_keep[wv];
        __syncthreads();
    }
    if (t == 0) slcnt[b] = base < SCAP ? base : SCAP;
}

// ---------------------------------------------------------------------------
// Kernel 4: exact fp32 scorer, 512 threads/block (unchanged)
// ---------------------------------------------------------------------------
__global__ __launch_bounds__(512) void exact_kernel(
    const float* __restrict__ AE,
    const float* __restrict__ Ws1, const float* __restrict__ bs1,
    const float* __restrict__ Ws2, const float* __restrict__ bs2g,
    const int* __restrict__ s_idx, const int* __restrict__ e_idx,
    const int* __restrict__ shortlist, const int* __restrict__ slcnt,
    float* __restrict__ scores)
{
    const int b  = blockIdx.y;
    const int n0 = blockIdx.x * 64;
    const int cntb = slcnt[b];
    if (n0 >= cntb) return;

    __shared__ float rsh[64][36];
    __shared__ float Ws[32][260];
    __shared__ int   ss[64], se[64], nn[64];

    const int t = threadIdx.x;
    if (t < 64) {
        int row = n0 + t;
        int n = 0;
        if (row < cntb) n = shortlist[b * SCAP + row];
        nn[t] = (row < cntb) ? n : -1;
        ss[t] = s_idx[n]; se[t] = e_idx[n];
    }
    __syncthreads();

    const int tx = t & 31;
    const int ty = t >> 5;
    float acc[4][8];
#pragma unroll
    for (int i = 0; i < 4; ++i)
#pragma unroll
        for (int j = 0; j < 8; ++j) acc[i][j] = 0.f;

    const float* Abase = AE + (size_t)b * T * 512;

    for (int kk = 0; kk < 256; kk += 32) {
        __syncthreads();
        {
            int row = t >> 4, q4 = (t & 15) * 4;
#pragma unroll
            for (int q = 0; q < 4; ++q)
                *(float4*)&Ws[row][q4 + q * 64] =
                    *(const float4*)&Ws1[(size_t)(kk + row) * 256 + q4 + q * 64];
        }
        {
            int sp = t >> 3, k4 = (t & 7) * 4;
            const float* Ar = Abase + (size_t)ss[sp] * 512 + kk + k4;
            const float* Er = Abase + (size_t)se[sp] * 512 + 256 + kk + k4;
            float4 a = *(const float4*)Ar;
            float4 e = *(const float4*)Er;
            float4 v;
            v.x = fmaxf(a.x + e.x, 0.f); v.y = fmaxf(a.y + e.y, 0.f);
            v.z = fmaxf(a.z + e.z, 0.f); v.w = fmaxf(a.w + e.w, 0.f);
            *(float4*)&rsh[sp][k4] = v;
        }
        __syncthreads();
#pragma unroll
        for (int k4 = 0; k4 < 32; k4 += 4) {
            float w[4][8];
#pragma unroll
            for (int kq = 0; kq < 4; ++kq) {
                float4 w0 = *(const float4*)&Ws[k4 + kq][tx * 4];
                float4 w1 = *(const float4*)&Ws[k4 + kq][128 + tx * 4];
                w[kq][0] = w0.x; w[kq][1] = w0.y; w[kq][2] = w0.z; w[kq][3] = w0.w;
                w[kq][4] = w1.x; w[kq][5] = w1.y; w[kq][6] = w1.z; w[kq][7] = w1.w;
            }
#pragma unroll
            for (int i = 0; i < 4; ++i) {
                float4 rv = *(const float4*)&rsh[ty * 4 + i][k4];
                float rq[4] = {rv.x, rv.y, rv.z, rv.w};
#pragma unroll
                for (int kq = 0; kq < 4; ++kq)
#pragma unroll
                    for (int j = 0; j < 8; ++j)
                        acc[i][j] = fmaf(rq[kq], w[kq][j], acc[i][j]);
            }
        }
    }

    float b1[8], w2[8];
#pragma unroll
    for (int j = 0; j < 8; ++j) {
        int c = (j < 4) ? (tx * 4 + j) : (128 + tx * 4 + j - 4);
        b1[j] = bs1[c];
        w2[j] = Ws2[c];
    }
    const float bs2v = bs2g[0];
#pragma unroll
    for (int i = 0; i < 4; ++i) {
        int r = ty * 4 + i;
        float p = 0.f;
#pragma unroll
        for (int j = 0; j < 8; ++j)
            p += fmaxf(acc[i][j] + b1[j], 0.f) * w2[j];
#pragma unroll
        for (int off = 16; off > 0; off >>= 1)
            p += __shfl_down(p, off, 32);
        if (tx == 0) {
            int n = nn[r];
            if (n >= 0)
                scores[(size_t)b * NSPAN + n] = p + bs2v;
        }
    }
}

// ---------------------------------------------------------------------------
// Kernel 5: top-K over the shortlist (unchanged)
// ---------------------------------------------------------------------------
__global__ __launch_bounds__(256) void topk_kernel(
    const float* __restrict__ scores,
    const int* __restrict__ shortlist, const int* __restrict__ slcnt,
    int* __restrict__ top_idx, float* __restrict__ top_scores)
{
    const int b = blockIdx.x;
    const int t = threadIdx.x;
    const int cnt = slcnt[b];

    __shared__ unsigned su[SCAP];
    __shared__ int sn[SCAP];
    __shared__ int hist[256];
    __shared__ unsigned s_prefix;
    __shared__ int s_remaining;
    __shared__ int wave_eq[4], wave_keep[4];

    for (int i = t; i < cnt; i += 256) {
        int n = shortlist[b * SCAP + i];
        unsigned ub = __float_as_uint(scores[(size_t)b * NSPAN + n]);
        su[i] = (ub & 0x80000000u) ? ~ub : (ub | 0x80000000u);
        sn[i] = n;
    }
    __syncthreads();

    unsigned prefix = 0;
    int remaining = KTOP;
    for (int d = 3; d >= 0; --d) {
        hist[t] = 0;
        __syncthreads();
        const int sh = d * 8;
        for (int i = t; i < cnt; i += 256) {
            unsigned u = su[i];
            bool match = (d == 3) || ((u >> (sh + 8)) == (prefix >> (sh + 8)));
            if (match) atomicAdd(&hist[(u >> sh) & 255], 1);
        }
        __syncthreads();
        if (t == 0) {
            int acc = 0, v = 255;
            for (; v > 0; --v) {
                int h = hist[v];
                if (acc + h >= remaining) break;
                acc += h;
            }
            s_prefix = prefix | ((unsigned)v << sh);
            s_remaining = remaining - acc;
        }
        __syncthreads();
        prefix = s_prefix;
        remaining = s_remaining;
        __syncthreads();
    }
    const unsigned v = prefix;
    const int need_eq = remaining;

    const int wid = t >> 6, lane = t & 63;
    int base_eq = 0, base_keep = 0;
    const unsigned long long ltmask = (1ull << lane) - 1ull;
    for (int c0 = 0; c0 < cnt; c0 += 256) {
        int i = c0 + t;
        bool valid = i < cnt;
        unsigned u = valid ? su[i] : 0u;
        bool eq = valid && (u == v);
        bool gt = valid && (u > v);
        unsigned long long beq = __ballot(eq);
        int eq_before = __popcll(beq & ltmask);
        if (lane == 0) wave_eq[wid] = __popcll(beq);
        __syncthreads();
        int eqb = base_eq;
        for (int w = 0; w < wid; ++w) eqb += wave_eq[w];
        int eq_rank = eqb + eq_before;
        bool keep = gt || (eq && (eq_rank < need_eq));
        unsigned long long bk = __ballot(keep);
        int keep_before = __popcll(bk & ltmask);
        if (lane == 0) wave_keep[wid] = __popcll(bk);
        __syncthreads();
        int kb = base_keep;
        for (int w = 0; w < wid; ++w) kb += wave_keep[w];
        if (keep) {
            int pos = kb + keep_before;
            top_idx[b * KTOP + pos] = sn[i];
            unsigned fb = (u & 0x80000000u) ? (u & 0x7FFFFFFFu) : ~u;
            float f = __uint_as_float(fb);
            top_scores[b * KTOP + pos] = isinf(f) ? -1.0f : f;
        }
        for (int w = 0; w < 4; ++w) { base_eq += wave_eq[w]; base_keep += wave_keep[w]; }
        __syncthreads();
    }
}

// ---------------------------------------------------------------------------
// Kernel 6: final head (unchanged)
// ---------------------------------------------------------------------------
__global__ __launch_bounds__(256) void final_kernel(
    const float* __restrict__ AE,
    const int* __restrict__ s_idx, const int* __restrict__ e_idx,
    const int* __restrict__ maskp,
    const int* __restrict__ top_idx, const float* __restrict__ top_scores,
    const float* __restrict__ injv,
    const float* __restrict__ Wsec, const float* __restrict__ bsec,
    const float* __restrict__ Wpred, const float* __restrict__ bpredg,
    float* __restrict__ out)
{
    const int b = blockIdx.x >> 2;
    const int k0 = (blockIdx.x & 3) * 64;

    __shared__ float sh[64][36];
    __shared__ float Ws[32][260];
    __shared__ int ss[64], se[64];
    __shared__ float msk[64], tsc[64];

    const int t = threadIdx.x;
    if (t < 64) {
        int kidx = k0 + t;
        int n = top_idx[b * KTOP + kidx];
        int s = s_idx[n], e = e_idx[n];
        ss[t] = s; se[t] = e;
        msk[t] = (maskp[b * T + s] != 0 && maskp[b * T + e] != 0) ? 1.f : 0.f;
        tsc[t] = top_scores[b * KTOP + kidx];
    }
    __syncthreads();

    const int tx = t & 31;
    const int ty = t >> 5;
    float acc[8][8];
#pragma unroll
    for (int i = 0; i < 8; ++i)
#pragma unroll
        for (int j = 0; j < 8; ++j) acc[i][j] = 0.f;

    const float* Abase = AE + (size_t)b * T * 512;

    for (int kk = 0; kk < 256; kk += 32) {
        __syncthreads();
        {
            int c4 = (t & 63) * 4, r0 = t >> 6;
#pragma unroll
            for (int r8 = 0; r8 < 8; ++r8) {
                int row = r0 + r8 * 4;
                *(float4*)&Ws[row][c4] =
                    *(const float4*)&Wsec[(size_t)(kk + row) * 256 + c4];
            }
        }
        {
            int sp = t >> 2, k8 = (t & 3) * 8;
            const float* Ar = Abase + (size_t)ss[sp] * 512 + kk + k8;
            const float* Er = Abase + (size_t)se[sp] * 512 + 256 + kk + k8;
#pragma unroll
            for (int q = 0; q < 2; ++q) {
                float4 a = *(const float4*)&Ar[q * 4];
                float4 e = *(const float4*)&Er[q * 4];
                float4 v;
                v.x = a.x + e.x; v.y = a.y + e.y; v.z = a.z + e.z; v.w = a.w + e.w;
                *(float4*)&sh[sp][k8 + q * 4] = v;
            }
        }
        __syncthreads();
#pragma unroll
        for (int k4 = 0; k4 < 32; k4 += 4) {
            float w[4][8];
#pragma unroll
            for (int kq = 0; kq < 4; ++kq) {
                float4 w0 = *(const float4*)&Ws[k4 + kq][tx * 4];
                float4 w1 = *(const float4*)&Ws[k4 + kq][128 + tx * 4];
                w[kq][0] = w0.x; w[kq][1] = w0.y; w[kq][2] = w0.z; w[kq][3] = w0.w;
                w[kq][4] = w1.x; w[kq][5] = w1.y; w[kq][6] = w1.z; w[kq][7] = w1.w;
            }
#pragma unroll
            for (int i = 0; i < 8; ++i) {
                float4 rv = *(const float4*)&sh[ty * 8 + i][k4];
                float rq[4] = {rv.x, rv.y, rv.z, rv.w};
#pragma unroll
                for (int kq = 0; kq < 4; ++kq)
#pragma unroll
                    for (int j = 0; j < 8; ++j)
                        acc[i][j] = fmaf(rq[kq], w[kq][j], acc[i][j]);
            }
        }
    }

    float bsec_r[8], wpred_r[8], injr[8];
#pragma unroll
    for (int j = 0; j < 8; ++j) {
        int c = (j < 4) ? (tx * 4 + j) : (128 + tx * 4 + j - 4);
        bsec_r[j] = bsec[c];
        wpred_r[j] = Wpred[c];
        injr[j] = injv[b * H + c];
    }
    const float bp = bpredg[0];
#pragma unroll
    for (int i = 0; i < 8; ++i) {
        int r = ty * 8 + i;
        float p = 0.f;
#pragma unroll
        for (int j = 0; j < 8; ++j) {
            float sec = acc[i][j] + bsec_r[j];
            p += fmaxf(injr[j] + sec, 0.f) * wpred_r[j];
        }
#pragma unroll
        for (int off = 16; off > 0; off >>= 1)
            p += __shfl_down(p, off, 32);
        if (tx == 0) {
            float logit = p + bp + tsc[r];
            float prob = (1.f / (1.f + expf(-logit))) * msk[r];
            out[b * KTOP + k0 + r] = prob;
        }
    }
}

// ---------------------------------------------------------------------------
extern "C" void kernel_launch(void* const* d_in, const int* in_sizes, int n_in,
                              void* d_out, int out_size, void* d_ws, size_t ws_size,
                              hipStream_t stream) {
    const float* inputs  = (const float*)d_in[0];
    const int*   imask   = (const int*)d_in[1];
    const float* tie     = (const float*)d_in[2];
    const float* W_start = (const float*)d_in[3];
    const float* b_start = (const float*)d_in[4];
    const float* W_end   = (const float*)d_in[5];
    const float* b_end   = (const float*)d_in[6];
    const float* W_s1    = (const float*)d_in[7];
    const float* b_s1    = (const float*)d_in[8];
    const float* W_s2    = (const float*)d_in[9];
    const float* b_s2    = (const float*)d_in[10];
    const float* W_inj   = (const float*)d_in[11];
    const float* b_inj   = (const float*)d_in[12];
    const float* W_sec   = (const float*)d_in[13];
    const float* b_sec   = (const float*)d_in[14];
    const float* W_pred  = (const float*)d_in[15];
    const float* b_pred  = (const float*)d_in[16];
    float* out = (float*)d_out;

    float* AE         = (float*)d_ws;
    float* scores     = AE + (size_t)BB * T * 512;
    int*   s_idx      = (int*)(scores + (size_t)BB * NSPAN);
    int*   e_idx      = s_idx + NSPAN;
    int*   top_idx    = e_idx + NSPAN;
    float* top_scores = (float*)(top_idx + BB * KTOP);
    float* injv       = top_scores + BB * KTOP;
    unsigned short* Wpk = (unsigned short*)(injv + BB * H);
    int*   shortlist  = (int*)(Wpk + 65536);
    int*   slcnt      = shortlist + BB * SCAP;

    prep_kernel<<<321, 256, 0, stream>>>(s_idx, e_idx, W_s1, Wpk,
                                         tie, W_inj, b_inj, injv);
    proj_kernel<<<dim3(128, 4), 256, 0, stream>>>(inputs, W_start, b_start, W_end, b_end, AE);
    approx_kernel<<<256, 512, 0, stream>>>(AE, Wpk, b_s1, W_s2, b_s2,
                                           s_idx, e_idx, imask, scores);
    select_kernel<<<BB, 256, 0, stream>>>(scores, shortlist, slcnt);
    exact_kernel<<<dim3(16, BB), 512, 0, stream>>>(AE, W_s1, b_s1, W_s2, b_s2,
                                                   s_idx, e_idx, shortlist, slcnt, scores);
    topk_kernel<<<BB, 256, 0, stream>>>(scores, shortlist, slcnt, top_idx, top_scores);
    final_kernel<<<BB * 4, 256, 0, stream>>>(AE, s_idx, e_idx, imask, top_idx, top_scores,
                                             injv, W_sec, b_sec, W_pred, b_pred, out);
}

// Round 12
// 512.274 us; speedup vs baseline: 1.0508x; 1.0508x over previous
//
#include <hip/hip_runtime.h>
#include <hip/hip_bf16.h>
#include <math.h>

#define BB 64
#define T 128
#define DD 768
#define H 256
#define JJ 128
#define NSPAN 8256
#define KTOP 256
#define SCAP 1024
#define MARGIN 0.03f

typedef __attribute__((ext_vector_type(8))) short bf16x8;
typedef __attribute__((ext_vector_type(4))) float f32x4;

__device__ inline unsigned short bfrne(float x) {
    unsigned u = __float_as_uint(x);
    return (unsigned short)((u + 0x7FFFu + ((u >> 16) & 1u)) >> 16);
}

__device__ inline unsigned pk2(float x, float y) {
    float2 f; f.x = x; f.y = y;
    __hip_bfloat162 h = __float22bfloat162_rn(f);
    return *reinterpret_cast<unsigned*>(&h);
}

// ---------------------------------------------------------------------------
// Kernel 1 (fused prep+proj): blocks 0..511 = proj GEMM v3; 512 = idx tables;
// 513..768 = W_s1 bf16 fragment pack; 769..832 = injection projection.
// ---------------------------------------------------------------------------
__global__ __launch_bounds__(256) void prep_proj_kernel(
    const float* __restrict__ X,
    const float* __restrict__ Wa, const float* __restrict__ ba,
    const float* __restrict__ Wb, const float* __restrict__ bb,
    float* __restrict__ AE,
    int* __restrict__ s_idx, int* __restrict__ e_idx,
    const float* __restrict__ W1, unsigned short* __restrict__ Wpk,
    const float* __restrict__ tie, const float* __restrict__ Winj,
    const float* __restrict__ binj, float* __restrict__ injv)
{
    const int blk = blockIdx.x;
    const int t = threadIdx.x;

    if (blk >= 512) {
        const int pblk = blk - 512;
        if (pblk == 0) {
            if (t < T) {
                int s = t;
                int start = s * T - (s * (s - 1)) / 2;
                int len = T - s;
                for (int i = 0; i < len; ++i) {
                    s_idx[start + i] = s;
                    e_idx[start + i] = s + i;
                }
            }
        } else if (pblk <= 256) {
            int idx = (pblk - 1) * 256 + t;   // 65536 total
            int j  = idx & 7;
            int l  = (idx >> 3) & 63;
            int kc = (idx >> 9) & 7;
            int ct = idx >> 12;
            int k = kc * 32 + (l >> 4) * 8 + j;
            int n = ct * 16 + (l & 15);
            Wpk[idx] = bfrne(W1[k * 256 + n]);
        } else {
            int b = pblk - 257;
            __shared__ float tb[JJ];
            if (t < JJ) tb[t] = tie[b * JJ + t];
            __syncthreads();
            float a = binj[t];
            for (int j = 0; j < JJ; ++j)
                a = fmaf(tb[j], Winj[j * H + t], a);
            injv[b * H + t] = a;
        }
        return;
    }

    // ---- proj part: blk 0..511 -> (px 0..127, cb 0..3) ----
    const int px = blk & 127;
    const int cb = blk >> 7;
    const int m0 = px * 64;
    const float* W    = (cb < 2) ? Wa : Wb;
    const float* bias = (cb < 2) ? ba : bb;
    const int wc0 = (cb & 1) * 128;
    const int oc0 = (cb < 2) ? wc0 : (256 + wc0);

    __shared__ float Xs[64 * 36];
    __shared__ float Wl[32 * 132];

    const int tx = t & 15;
    const int ty = t >> 4;

    const int xrow = t >> 2;
    const int xk8  = (t & 3) * 8;
    const int wrow = t >> 4;
    const int wcol = (t & 15) * 8;

    float4 xr[2], w0r[2], w1r[2];
    {
        const float* xp = &X[(size_t)(m0 + xrow) * DD + xk8];
        xr[0] = *(const float4*)&xp[0]; xr[1] = *(const float4*)&xp[4];
        const float* wp0 = &W[(size_t)wrow * 256 + wc0 + wcol];
        w0r[0] = *(const float4*)&wp0[0]; w0r[1] = *(const float4*)&wp0[4];
        const float* wp1 = &W[(size_t)(wrow + 16) * 256 + wc0 + wcol];
        w1r[0] = *(const float4*)&wp1[0]; w1r[1] = *(const float4*)&wp1[4];
    }

    float acc[4][8];
#pragma unroll
    for (int i = 0; i < 4; ++i)
#pragma unroll
        for (int j = 0; j < 8; ++j) acc[i][j] = 0.f;

    for (int it = 0; it < 24; ++it) {
        __syncthreads();
        *(float4*)&Xs[xrow * 36 + xk8]           = xr[0];
        *(float4*)&Xs[xrow * 36 + xk8 + 4]       = xr[1];
        *(float4*)&Wl[wrow * 132 + wcol]         = w0r[0];
        *(float4*)&Wl[wrow * 132 + wcol + 4]     = w0r[1];
        *(float4*)&Wl[(wrow+16) * 132 + wcol]    = w1r[0];
        *(float4*)&Wl[(wrow+16) * 132 + wcol + 4]= w1r[1];
        __syncthreads();
        if (it + 1 < 24) {
            const int kk = (it + 1) * 32;
            const float* xp = &X[(size_t)(m0 + xrow) * DD + kk + xk8];
            xr[0] = *(const float4*)&xp[0]; xr[1] = *(const float4*)&xp[4];
            const float* wp0 = &W[(size_t)(kk + wrow) * 256 + wc0 + wcol];
            w0r[0] = *(const float4*)&wp0[0]; w0r[1] = *(const float4*)&wp0[4];
            const float* wp1 = &W[(size_t)(kk + wrow + 16) * 256 + wc0 + wcol];
            w1r[0] = *(const float4*)&wp1[0]; w1r[1] = *(const float4*)&wp1[4];
        }
#pragma unroll
        for (int k = 0; k < 32; ++k) {
            float4 wv0 = *(const float4*)&Wl[k * 132 + tx * 8];
            float4 wv1 = *(const float4*)&Wl[k * 132 + tx * 8 + 4];
            float wq[8] = {wv0.x, wv0.y, wv0.z, wv0.w, wv1.x, wv1.y, wv1.z, wv1.w};
            float xq[4];
#pragma unroll
            for (int i = 0; i < 4; ++i)
                xq[i] = Xs[(ty * 4 + i) * 36 + k];
#pragma unroll
            for (int i = 0; i < 4; ++i)
#pragma unroll
                for (int j = 0; j < 8; ++j)
                    acc[i][j] = fmaf(xq[i], wq[j], acc[i][j]);
        }
    }

    float bq[8];
#pragma unroll
    for (int j = 0; j < 8; ++j) bq[j] = bias[wc0 + tx * 8 + j];
#pragma unroll
    for (int i = 0; i < 4; ++i) {
        const size_t row = m0 + ty * 4 + i;
        float4 o0, o1;
        o0.x = acc[i][0] + bq[0]; o0.y = acc[i][1] + bq[1];
        o0.z = acc[i][2] + bq[2]; o0.w = acc[i][3] + bq[3];
        o1.x = acc[i][4] + bq[4]; o1.y = acc[i][5] + bq[5];
        o1.z = acc[i][6] + bq[6]; o1.w = acc[i][7] + bq[7];
        *(float4*)&AE[row * 512 + oc0 + tx * 8]     = o0;
        *(float4*)&AE[row * 512 + oc0 + tx * 8 + 4] = o1;
    }
}

// ---------------------------------------------------------------------------
// Kernel 2: approx scorer — R10 version verbatim (software-pipelined tiles,
// 512 blocks x 512 threads, XCD-local batch mapping). Proven 133 us.
// ---------------------------------------------------------------------------
__global__ __launch_bounds__(512, 4) void approx_kernel(
    const float* __restrict__ AE,
    const unsigned short* __restrict__ Wpk,
    const float* __restrict__ bs1, const float* __restrict__ Ws2,
    const float* __restrict__ bs2g,
    const int* __restrict__ s_idx, const int* __restrict__ e_idx,
    const int* __restrict__ maskp,
    float* __restrict__ scores)
{
    const int bid   = blockIdx.x;       // 0..511
    const int r     = bid & 7;
    const int q     = bid >> 3;         // 0..63
    const int g     = q >> 3;
    const int chunk = q & 7;
    const int b     = g * 8 + r;
    const int tile0 = chunk * 65;
    const int tcnt  = (516 - tile0 < 65) ? (516 - tile0) : 65;

    __shared__ __align__(16) unsigned short rshf[2][8][64][8];  // 16 KB
    __shared__ float pslice[2][8][16];                          // 1 KB

    const int t      = threadIdx.x;
    const int w      = t >> 6;
    const int lane   = t & 63;
    const int lrow16 = lane & 15;
    const int quad   = lane >> 4;

    // held B fragments: ct = 2w + c (read once per kernel)
    bf16x8 bfr[2][8];
    float b1c[2], w2c[2];
#pragma unroll
    for (int c = 0; c < 2; ++c) {
#pragma unroll
        for (int kc = 0; kc < 8; ++kc)
            bfr[c][kc] = *(const bf16x8*)&Wpk[((((2 * w + c) * 8 + kc) * 64) + lane) * 8];
        int col = (2 * w + c) * 16 + lrow16;
        b1c[c] = bs1[col];
        w2c[c] = Ws2[col];
    }
    const float bs2v = bs2g[0];

    const float* Abase = AE + (size_t)b * T * 512;
    const int sp   = t >> 5;
    const int km   = t & 31;
    const int kc_s = km >> 2;
    const int q_s  = km & 3;
    const int slot = (q_s * 16 + sp + kc_s) & 63;

    // prologue: stage tile0 into buffer 0
    {
        int n = tile0 * 16 + sp;
        int s = s_idx[n], e = e_idx[n];
        const float* Ar = Abase + (size_t)s * 512 + km * 8;
        const float* Er = Abase + (size_t)e * 512 + 256 + km * 8;
        float4 a0 = *(const float4*)&Ar[0];
        float4 a1 = *(const float4*)&Ar[4];
        float4 e0 = *(const float4*)&Er[0];
        float4 e1 = *(const float4*)&Er[4];
        uint4 v;
        v.x = pk2(fmaxf(a0.x + e0.x, 0.f), fmaxf(a0.y + e0.y, 0.f));
        v.y = pk2(fmaxf(a0.z + e0.z, 0.f), fmaxf(a0.w + e0.w, 0.f));
        v.z = pk2(fmaxf(a1.x + e1.x, 0.f), fmaxf(a1.y + e1.y, 0.f));
        v.w = pk2(fmaxf(a1.z + e1.z, 0.f), fmaxf(a1.w + e1.w, 0.f));
        *(uint4*)&rshf[0][kc_s][slot][0] = v;
    }
    __syncthreads();

    for (int tt = 0; tt < tcnt; ++tt) {
        const int cur = tt & 1;
        float4 a0, a1, e0, e1;
        const bool pf = (tt + 1 < tcnt);
        if (pf) {
            int n = (tile0 + tt + 1) * 16 + sp;
            int s = s_idx[n], e = e_idx[n];
            const float* Ar = Abase + (size_t)s * 512 + km * 8;
            const float* Er = Abase + (size_t)e * 512 + 256 + km * 8;
            a0 = *(const float4*)&Ar[0];
            a1 = *(const float4*)&Ar[4];
            e0 = *(const float4*)&Er[0];
            e1 = *(const float4*)&Er[4];
        }
        f32x4 acc0 = {0.f, 0.f, 0.f, 0.f};
        f32x4 acc1 = {0.f, 0.f, 0.f, 0.f};
#pragma unroll
        for (int kc = 0; kc < 8; ++kc) {
            bf16x8 a = *(const bf16x8*)&rshf[cur][kc][(lane + kc) & 63][0];
            acc0 = __builtin_amdgcn_mfma_f32_16x16x32_bf16(a, bfr[0][kc], acc0, 0, 0, 0);
            acc1 = __builtin_amdgcn_mfma_f32_16x16x32_bf16(a, bfr[1][kc], acc1, 0, 0, 0);
        }
        float ps[4];
#pragma unroll
        for (int rr = 0; rr < 4; ++rr)
            ps[rr] = fmaxf(acc0[rr] + b1c[0], 0.f) * w2c[0]
                   + fmaxf(acc1[rr] + b1c[1], 0.f) * w2c[1];
#pragma unroll
        for (int off = 1; off < 16; off <<= 1)
#pragma unroll
            for (int rr = 0; rr < 4; ++rr)
                ps[rr] += __shfl_xor(ps[rr], off, 16);
        if (lrow16 == 0) {
            float4 v; v.x = ps[0]; v.y = ps[1]; v.z = ps[2]; v.w = ps[3];
            *(float4*)&pslice[cur][w][quad * 4] = v;
        }
        if (pf) {
            uint4 v;
            v.x = pk2(fmaxf(a0.x + e0.x, 0.f), fmaxf(a0.y + e0.y, 0.f));
            v.y = pk2(fmaxf(a0.z + e0.z, 0.f), fmaxf(a0.w + e0.w, 0.f));
            v.z = pk2(fmaxf(a1.x + e1.x, 0.f), fmaxf(a1.y + e1.y, 0.f));
            v.w = pk2(fmaxf(a1.z + e1.z, 0.f), fmaxf(a1.w + e1.w, 0.f));
            *(uint4*)&rshf[cur ^ 1][kc_s][slot][0] = v;
        }
        __syncthreads();
        if (t < 16) {
            int n = (tile0 + tt) * 16 + t;
            float sc = bs2v;
#pragma unroll
            for (int ww = 0; ww < 8; ++ww) sc += pslice[cur][ww][t];
            int s = s_idx[n], e = e_idx[n];
            bool m = (maskp[b * T + s] != 0) && (maskp[b * T + e] != 0);
            scores[(size_t)b * NSPAN + n] = m ? sc : -INFINITY;
        }
    }
}

// ---------------------------------------------------------------------------
// Kernel 3: shortlist select — byte radix, 1024 threads (compaction 33->9 chunks)
// ---------------------------------------------------------------------------
__global__ __launch_bounds__(1024) void select_kernel(
    const float* __restrict__ scores,
    int* __restrict__ shortlist, int* __restrict__ slcnt)
{
    const int b = blockIdx.x;
    const int t = threadIdx.x;
    __shared__ unsigned su[NSPAN];
    __shared__ int hist[256];
    __shared__ unsigned s_prefix;
    __shared__ int s_remaining;
    __shared__ int wave_keep[16];

    const float* sc = scores + (size_t)b * NSPAN;
    for (int i = t; i < NSPAN; i += 1024) {
        unsigned ub = __float_as_uint(sc[i]);
        su[i] = (ub & 0x80000000u) ? ~ub : (ub | 0x80000000u);
    }
    __syncthreads();

    unsigned prefix = 0;
    int remaining = KTOP;
    for (int d = 3; d >= 0; --d) {
        if (t < 256) hist[t] = 0;
        __syncthreads();
        const int sh = d * 8;
        for (int i = t; i < NSPAN; i += 1024) {
            unsigned u = su[i];
            bool match = (d == 3) || ((u >> (sh + 8)) == (prefix >> (sh + 8)));
            if (match) atomicAdd(&hist[(u >> sh) & 255], 1);
        }
        __syncthreads();
        if (t == 0) {
            int acc = 0, v = 255;
            for (; v > 0; --v) {
                int h = hist[v];
                if (acc + h >= remaining) break;
                acc += h;
            }
            s_prefix = prefix | ((unsigned)v << sh);
            s_remaining = remaining - acc;
        }
        __syncthreads();
        prefix = s_prefix;
        remaining = s_remaining;
        __syncthreads();
    }

    unsigned ub = (prefix & 0x80000000u) ? (prefix & 0x7FFFFFFFu) : ~prefix;
    float kthf = __uint_as_float(ub);
    float tau = kthf - MARGIN;
    unsigned tb = __float_as_uint(tau);
    unsigned ktau = (tb & 0x80000000u) ? ~tb : (tb | 0x80000000u);

    const int wid = t >> 6, lane = t & 63;
    int base = 0;
    const unsigned long long ltmask = (1ull << lane) - 1ull;
    for (int c0 = 0; c0 < NSPAN; c0 += 1024) {
        int n = c0 + t;
        bool keep = (n < NSPAN) && (su[n] >= ktau);
        unsigned long long bk = __ballot(keep);
        int before = __popcll(bk & ltmask);
        if (lane == 0) wave_keep[wid] = __popcll(bk);
        __syncthreads();
        int kb = base;
        for (int wv = 0; wv < wid; ++wv) kb += wave_keep[wv];
        if (keep) {
            int pos = kb + before;
            if (pos < SCAP) shortlist[b * SCAP + pos] = n;
        }
        for (int wv = 0; wv < 16; ++wv) base += wave_keep[wv];
        __syncthreads();
    }
    if (t == 0) slcnt[b] = base < SCAP ? base : SCAP;
}

// ---------------------------------------------------------------------------
// Kernel 4: exact fp32 scorer, 512 threads/block (unchanged)
// ---------------------------------------------------------------------------
__global__ __launch_bounds__(512) void exact_kernel(
    const float* __restrict__ AE,
    const float* __restrict__ Ws1, const float* __restrict__ bs1,
    const float* __restrict__ Ws2, const float* __restrict__ bs2g,
    const int* __restrict__ s_idx, const int* __restrict__ e_idx,
    const int* __restrict__ shortlist, const int* __restrict__ slcnt,
    float* __restrict__ scores)
{
    const int b  = blockIdx.y;
    const int n0 = blockIdx.x * 64;
    const int cntb = slcnt[b];
    if (n0 >= cntb) return;

    __shared__ float rsh[64][36];
    __shared__ float Ws[32][260];
    __shared__ int   ss[64], se[64], nn[64];

    const int t = threadIdx.x;
    if (t < 64) {
        int row = n0 + t;
        int n = 0;
        if (row < cntb) n = shortlist[b * SCAP + row];
        nn[t] = (row < cntb) ? n : -1;
        ss[t] = s_idx[n]; se[t] = e_idx[n];
    }
    __syncthreads();

    const int tx = t & 31;
    const int ty = t >> 5;
    float acc[4][8];
#pragma unroll
    for (int i = 0; i < 4; ++i)
#pragma unroll
        for (int j = 0; j < 8; ++j) acc[i][j] = 0.f;

    const float* Abase = AE + (size_t)b * T * 512;

    for (int kk = 0; kk < 256; kk += 32) {
        __syncthreads();
        {
            int row = t >> 4, q4 = (t & 15) * 4;
#pragma unroll
            for (int q = 0; q < 4; ++q)
                *(float4*)&Ws[row][q4 + q * 64] =
                    *(const float4*)&Ws1[(size_t)(kk + row) * 256 + q4 + q * 64];
        }
        {
            int sp = t >> 3, k4 = (t & 7) * 4;
            const float* Ar = Abase + (size_t)ss[sp] * 512 + kk + k4;
            const float* Er = Abase + (size_t)se[sp] * 512 + 256 + kk + k4;
            float4 a = *(const float4*)Ar;
            float4 e = *(const float4*)Er;
            float4 v;
            v.x = fmaxf(a.x + e.x, 0.f); v.y = fmaxf(a.y + e.y, 0.f);
            v.z = fmaxf(a.z + e.z, 0.f); v.w = fmaxf(a.w + e.w, 0.f);
            *(float4*)&rsh[sp][k4] = v;
        }
        __syncthreads();
#pragma unroll
        for (int k4 = 0; k4 < 32; k4 += 4) {
            float w[4][8];
#pragma unroll
            for (int kq = 0; kq < 4; ++kq) {
                float4 w0 = *(const float4*)&Ws[k4 + kq][tx * 4];
                float4 w1 = *(const float4*)&Ws[k4 + kq][128 + tx * 4];
                w[kq][0] = w0.x; w[kq][1] = w0.y; w[kq][2] = w0.z; w[kq][3] = w0.w;
                w[kq][4] = w1.x; w[kq][5] = w1.y; w[kq][6] = w1.z; w[kq][7] = w1.w;
            }
#pragma unroll
            for (int i = 0; i < 4; ++i) {
                float4 rv = *(const float4*)&rsh[ty * 4 + i][k4];
                float rq[4] = {rv.x, rv.y, rv.z, rv.w};
#pragma unroll
                for (int kq = 0; kq < 4; ++kq)
#pragma unroll
                    for (int j = 0; j < 8; ++j)
                        acc[i][j] = fmaf(rq[kq], w[kq][j], acc[i][j]);
            }
        }
    }

    float b1[8], w2[8];
#pragma unroll
    for (int j = 0; j < 8; ++j) {
        int c = (j < 4) ? (tx * 4 + j) : (128 + tx * 4 + j - 4);
        b1[j] = bs1[c];
        w2[j] = Ws2[c];
    }
    const float bs2v = bs2g[0];
#pragma unroll
    for (int i = 0; i < 4; ++i) {
        int r = ty * 4 + i;
        float p = 0.f;
#pragma unroll
        for (int j = 0; j < 8; ++j)
            p += fmaxf(acc[i][j] + b1[j], 0.f) * w2[j];
#pragma unroll
        for (int off = 16; off > 0; off >>= 1)
            p += __shfl_down(p, off, 32);
        if (tx == 0) {
            int n = nn[r];
            if (n >= 0)
                scores[(size_t)b * NSPAN + n] = p + bs2v;
        }
    }
}

// ---------------------------------------------------------------------------
// Kernel 5: top-K over the shortlist — 1024 threads (single compaction chunk)
// ---------------------------------------------------------------------------
__global__ __launch_bounds__(1024) void topk_kernel(
    const float* __restrict__ scores,
    const int* __restrict__ shortlist, const int* __restrict__ slcnt,
    int* __restrict__ top_idx, float* __restrict__ top_scores)
{
    const int b = blockIdx.x;
    const int t = threadIdx.x;
    const int cnt = slcnt[b];

    __shared__ unsigned su[SCAP];
    __shared__ int sn[SCAP];
    __shared__ int hist[256];
    __shared__ unsigned s_prefix;
    __shared__ int s_remaining;
    __shared__ int wave_eq[16], wave_keep[16];

    for (int i = t; i < cnt; i += 1024) {
        int n = shortlist[b * SCAP + i];
        unsigned ub = __float_as_uint(scores[(size_t)b * NSPAN + n]);
        su[i] = (ub & 0x80000000u) ? ~ub : (ub | 0x80000000u);
        sn[i] = n;
    }
    __syncthreads();

    unsigned prefix = 0;
    int remaining = KTOP;
    for (int d = 3; d >= 0; --d) {
        if (t < 256) hist[t] = 0;
        __syncthreads();
        const int sh = d * 8;
        for (int i = t; i < cnt; i += 1024) {
            unsigned u = su[i];
            bool match = (d == 3) || ((u >> (sh + 8)) == (prefix >> (sh + 8)));
            if (match) atomicAdd(&hist[(u >> sh) & 255], 1);
        }
        __syncthreads();
        if (t == 0) {
            int acc = 0, v = 255;
            for (; v > 0; --v) {
                int h = hist[v];
                if (acc + h >= remaining) break;
                acc += h;
            }
            s_prefix = prefix | ((unsigned)v << sh);
            s_remaining = remaining - acc;
        }
        __syncthreads();
        prefix = s_prefix;
        remaining = s_remaining;
        __syncthreads();
    }
    const unsigned v = prefix;
    const int need_eq = remaining;

    const int wid = t >> 6, lane = t & 63;
    int base_eq = 0, base_keep = 0;
    const unsigned long long ltmask = (1ull << lane) - 1ull;
    for (int c0 = 0; c0 < cnt; c0 += 1024) {
        int i = c0 + t;
        bool valid = i < cnt;
        unsigned u = valid ? su[i] : 0u;
        bool eq = valid && (u == v);
        bool gt = valid && (u > v);
        unsigned long long beq = __ballot(eq);
        int eq_before = __popcll(beq & ltmask);
        if (lane == 0) wave_eq[wid] = __popcll(beq);
        __syncthreads();
        int eqb = base_eq;
        for (int w = 0; w < wid; ++w) eqb += wave_eq[w];
        int eq_rank = eqb + eq_before;
        bool keep = gt || (eq && (eq_rank < need_eq));
        unsigned long long bk = __ballot(keep);
        int keep_before = __popcll(bk & ltmask);
        if (lane == 0) wave_keep[wid] = __popcll(bk);
        __syncthreads();
        int kb = base_keep;
        for (int w = 0; w < wid; ++w) kb += wave_keep[w];
        if (keep) {
            int pos = kb + keep_before;
            top_idx[b * KTOP + pos] = sn[i];
            unsigned fb = (u & 0x80000000u) ? (u & 0x7FFFFFFFu) : ~u;
            float f = __uint_as_float(fb);
            top_scores[b * KTOP + pos] = isinf(f) ? -1.0f : f;
        }
        for (int w = 0; w < 16; ++w) { base_eq += wave_eq[w]; base_keep += wave_keep[w]; }
        __syncthreads();
    }
}

// ---------------------------------------------------------------------------
// Kernel 6: final head (unchanged)
// ---------------------------------------------------------------------------
__global__ __launch_bounds__(256) void final_kernel(
    const float* __restrict__ AE,
    const int* __restrict__ s_idx, const int* __restrict__ e_idx,
    const int* __restrict__ maskp,
    const int* __restrict__ top_idx, const float* __restrict__ top_scores,
    const float* __restrict__ injv,
    const float* __restrict__ Wsec, const float* __restrict__ bsec,
    const float* __restrict__ Wpred, const float* __restrict__ bpredg,
    float* __restrict__ out)
{
    const int b = blockIdx.x >> 2;
    const int k0 = (blockIdx.x & 3) * 64;

    __shared__ float sh[64][36];
    __shared__ float Ws[32][260];
    __shared__ int ss[64], se[64];
    __shared__ float msk[64], tsc[64];

    const int t = threadIdx.x;
    if (t < 64) {
        int kidx = k0 + t;
        int n = top_idx[b * KTOP + kidx];
        int s = s_idx[n], e = e_idx[n];
        ss[t] = s; se[t] = e;
        msk[t] = (maskp[b * T + s] != 0 && maskp[b * T + e] != 0) ? 1.f : 0.f;
        tsc[t] = top_scores[b * KTOP + kidx];
    }
    __syncthreads();

    const int tx = t & 31;
    const int ty = t >> 5;
    float acc[8][8];
#pragma unroll
    for (int i = 0; i < 8; ++i)
#pragma unroll
        for (int j = 0; j < 8; ++j) acc[i][j] = 0.f;

    const float* Abase = AE + (size_t)b * T * 512;

    for (int kk = 0; kk < 256; kk += 32) {
        __syncthreads();
        {
            int c4 = (t & 63) * 4, r0 = t >> 6;
#pragma unroll
            for (int r8 = 0; r8 < 8; ++r8) {
                int row = r0 + r8 * 4;
                *(float4*)&Ws[row][c4] =
                    *(const float4*)&Wsec[(size_t)(kk + row) * 256 + c4];
            }
        }
        {
            int sp = t >> 2, k8 = (t & 3) * 8;
            const float* Ar = Abase + (size_t)ss[sp] * 512 + kk + k8;
            const float* Er = Abase + (size_t)se[sp] * 512 + 256 + kk + k8;
#pragma unroll
            for (int q = 0; q < 2; ++q) {
                float4 a = *(const float4*)&Ar[q * 4];
                float4 e = *(const float4*)&Er[q * 4];
                float4 v;
                v.x = a.x + e.x; v.y = a.y + e.y; v.z = a.z + e.z; v.w = a.w + e.w;
                *(float4*)&sh[sp][k8 + q * 4] = v;
            }
        }
        __syncthreads();
#pragma unroll
        for (int k4 = 0; k4 < 32; k4 += 4) {
            float w[4][8];
#pragma unroll
            for (int kq = 0; kq < 4; ++kq) {
                float4 w0 = *(const float4*)&Ws[k4 + kq][tx * 4];
                float4 w1 = *(const float4*)&Ws[k4 + kq][128 + tx * 4];
                w[kq][0] = w0.x; w[kq][1] = w0.y; w[kq][2] = w0.z; w[kq][3] = w0.w;
                w[kq][4] = w1.x; w[kq][5] = w1.y; w[kq][6] = w1.z; w[kq][7] = w1.w;
            }
#pragma unroll
            for (int i = 0; i < 8; ++i) {
                float4 rv = *(const float4*)&sh[ty * 8 + i][k4];
                float rq[4] = {rv.x, rv.y, rv.z, rv.w};
#pragma unroll
                for (int kq = 0; kq < 4; ++kq)
#pragma unroll
                    for (int j = 0; j < 8; ++j)
                        acc[i][j] = fmaf(rq[kq], w[kq][j], acc[i][j]);
            }
        }
    }

    float bsec_r[8], wpred_r[8], injr[8];
#pragma unroll
    for (int j = 0; j < 8; ++j) {
        int c = (j < 4) ? (tx * 4 + j) : (128 + tx * 4 + j - 4);
        bsec_r[j] = bsec[c];
        wpred_r[j] = Wpred[c];
        injr[j] = injv[b * H + c];
    }
    const float bp = bpredg[0];
#pragma unroll
    for (int i = 0; i < 8; ++i) {
        int r = ty * 8 + i;
        float p = 0.f;
#pragma unroll
        for (int j = 0; j < 8; ++j) {
            float sec = acc[i][j] + bsec_r[j];
            p += fmaxf(injr[j] + sec, 0.f) * wpred_r[j];
        }
#pragma unroll
        for (int off = 16; off > 0; off >>= 1)
            p += __shfl_down(p, off, 32);
        if (tx == 0) {
            float logit = p + bp + tsc[r];
            float prob = (1.f / (1.f + expf(-logit))) * msk[r];
            out[b * KTOP + k0 + r] = prob;
        }
    }
}

// ---------------------------------------------------------------------------
extern "C" void kernel_launch(void* const* d_in, const int* in_sizes, int n_in,
                              void* d_out, int out_size, void* d_ws, size_t ws_size,
                              hipStream_t stream) {
    const float* inputs  = (const float*)d_in[0];
    const int*   imask   = (const int*)d_in[1];
    const float* tie     = (const float*)d_in[2];
    const float* W_start = (const float*)d_in[3];
    const float* b_start = (const float*)d_in[4];
    const float* W_end   = (const float*)d_in[5];
    const float* b_end   = (const float*)d_in[6];
    const float* W_s1    = (const float*)d_in[7];
    const float* b_s1    = (const float*)d_in[8];
    const float* W_s2    = (const float*)d_in[9];
    const float* b_s2    = (const float*)d_in[10];
    const float* W_inj   = (const float*)d_in[11];
    const float* b_inj   = (const float*)d_in[12];
    const float* W_sec   = (const float*)d_in[13];
    const float* b_sec   = (const float*)d_in[14];
    const float* W_pred  = (const float*)d_in[15];
    const float* b_pred  = (const float*)d_in[16];
    float* out = (float*)d_out;

    float* AE         = (float*)d_ws;
    float* scores     = AE + (size_t)BB * T * 512;
    int*   s_idx      = (int*)(scores + (size_t)BB * NSPAN);
    int*   e_idx      = s_idx + NSPAN;
    int*   top_idx    = e_idx + NSPAN;
    float* top_scores = (float*)(top_idx + BB * KTOP);
    float* injv       = top_scores + BB * KTOP;
    unsigned short* Wpk = (unsigned short*)(injv + BB * H);
    int*   shortlist  = (int*)(Wpk + 65536);
    int*   slcnt      = shortlist + BB * SCAP;

    prep_proj_kernel<<<833, 256, 0, stream>>>(inputs, W_start, b_start, W_end, b_end, AE,
                                              s_idx, e_idx, W_s1, Wpk,
                                              tie, W_inj, b_inj, injv);
    approx_kernel<<<512, 512, 0, stream>>>(AE, Wpk, b_s1, W_s2, b_s2,
                                           s_idx, e_idx, imask, scores);
    select_kernel<<<BB, 1024, 0, stream>>>(scores, shortlist, slcnt);
    exact_kernel<<<dim3(16, BB), 512, 0, stream>>>(AE, W_s1, b_s1, W_s2, b_s2,
                                                   s_idx, e_idx, shortlist, slcnt, scores);
    topk_kernel<<<BB, 1024, 0, stream>>>(scores, shortlist, slcnt, top_idx, top_scores);
    final_kernel<<<BB * 4, 256, 0, stream>>>(AE, s_idx, e_idx, imask, top_idx, top_scores,
                                             injv, W_sec, b_sec, W_pred, b_pred, out);
}